// Round 4
// baseline (196.808 us; speedup 1.0000x reference)
//
#include <hip/hip_runtime.h>
#include <hip/hip_bf16.h>

// out[b] = X[b] @ (X[b]^T @ X[b]);  B=8, S=4096, D=512, fp32 in/out.
// Pipeline (bf16 MFMA, fp32 accumulate), ws = 268MB observed:
//   k1: Xt[d][s] bf16 -> d_out[0:33.5M) ; Xb16[s][d] bf16 -> ws+4.2M
//   k2: split-K=8 gram partials fp32 -> ws+37.7M  (XCD-swizzled: chunk->one XCD)
//   kr: reduce 8 partials -> bf16 gram -> ws[0:4.2M)
//   k3: out = Xb16 . gram^T (both K-contig, async-LDS, XCD-swizzled) -> d_out

typedef __attribute__((ext_vector_type(8))) short short8;
typedef __attribute__((ext_vector_type(4))) float floatx4;

#define BM 128
#define BN 128
#define BK 32

#define BATCH 8
#define SEQ 4096
#define DIM 512

__device__ __forceinline__ void async_copy16(const __hip_bfloat16* g, __hip_bfloat16* l) {
  __builtin_amdgcn_global_load_lds((const __attribute__((address_space(1))) void*)g,
                                   (__attribute__((address_space(3))) void*)l, 16, 0, 0);
}

// ---------------- k1: transpose+cast (Xt) and optional straight cast (Xb16) --
__global__ __launch_bounds__(256) void transpose_cast_kernel(
    const float* __restrict__ X, __hip_bfloat16* __restrict__ Xt,
    __hip_bfloat16* __restrict__ Xb16) {
  __shared__ float tile[64][65];
  const int b = blockIdx.z;
  const int s0 = blockIdx.x * 64;
  const int d0 = blockIdx.y * 64;
  const int tid = threadIdx.x;
  const int tx = tid & 63;
  const int ty = tid >> 6;  // 0..3
  const float* Xb = X + (long)b * SEQ * DIM;
  __hip_bfloat16* Xtb = Xt + (long)b * DIM * SEQ;
#pragma unroll
  for (int r = 0; r < 64; r += 4)
    tile[r + ty][tx] = Xb[(long)(s0 + r + ty) * DIM + d0 + tx];
  __syncthreads();
  // Xt[d][s]: pack 8 consecutive s per 16B store.
#pragma unroll
  for (int it = 0; it < 2; ++it) {
    const int idx = it * 256 + tid;    // 0..511
    const int dl = idx >> 3;           // 0..63
    const int so = (idx & 7) * 8;      // 0,8,..,56
    union { short8 v; __hip_bfloat16 e[8]; } u;
#pragma unroll
    for (int j = 0; j < 8; ++j) u.e[j] = __float2bfloat16(tile[so + j][dl]);
    *(short8*)&Xtb[(long)(d0 + dl) * SEQ + s0 + so] = u.v;
  }
  // Xb16[s][d]: straight cast, pack 8 consecutive d per 16B store.
  if (Xb16 != nullptr) {
    __hip_bfloat16* Xcb = Xb16 + (long)b * SEQ * DIM;
#pragma unroll
    for (int it = 0; it < 2; ++it) {
      const int idx = it * 256 + tid;  // 0..511
      const int sl = idx >> 3;         // 0..63
      const int dc = idx & 7;          // 8-wide d chunk
      union { short8 v; __hip_bfloat16 e[8]; } u;
#pragma unroll
      for (int j = 0; j < 8; ++j) u.e[j] = __float2bfloat16(tile[sl][dc * 8 + j]);
      *(short8*)&Xcb[(long)(s0 + sl) * DIM + d0 + dc * 8] = u.v;
    }
  }
}

// ---------------- GEMM: C = A . Bt^T (Bt stored [N][K], K-contiguous) -------
// NSPLIT: split-K factor. AFP32: A fp32 cast-in-staging w/ register prefetch.
// SWZ=0: grid(x=ntile_n, y=ntile_m, z=B*NSPLIT) standard.
// SWZ=1: grid(128,1,B) k3-style: m-slab's 4 n-blocks share an XCD.
// SWZ=2: grid(B*NSPLIT,16,1) k2-style: all 16 tiles of one (b,split) chunk on
//        one XCD (linear id === bz mod 8); per-XCD set = 4MB = its L2.
template <int NSPLIT, bool AFP32, int SWZ>
__global__ __launch_bounds__(256) void gemm_bt_kernel(
    const float* __restrict__ Af, const __hip_bfloat16* __restrict__ Ab,
    const __hip_bfloat16* __restrict__ Bt, float* __restrict__ C,
    int K, int lda, int ldb, int ldc, long strideA, long strideB, long strideC) {
  __shared__ __align__(16) __hip_bfloat16 As[BM * BK];  // [m][k]
  __shared__ __align__(16) __hip_bfloat16 Bs[BN * BK];  // [n][k]

  int bz, m0, n0;
  if constexpr (SWZ == 1) {
    const int lin = blockIdx.x;        // 0..127 per batch
    bz = blockIdx.z;
    const int xcd = lin & 7;
    const int t = lin >> 3;            // 0..15
    n0 = (t & 3) * BN;
    m0 = ((t >> 2) * 8 + xcd) * BM;
  } else if constexpr (SWZ == 2) {
    bz = blockIdx.x;                   // chunk id, fastest dim -> xcd = bz & 7
    const int t = blockIdx.y;          // 0..15 tile
    m0 = (t >> 2) * BM;
    n0 = (t & 3) * BN;
  } else {
    bz = blockIdx.z;
    m0 = blockIdx.y * BM;
    n0 = blockIdx.x * BN;
  }
  const int b = bz / NSPLIT;
  const int split = bz % NSPLIT;
  const int klen = K / NSPLIT;
  const int kb = split * klen;

  const int tid = threadIdx.x;
  const int w = tid >> 6;
  const int lane = tid & 63;
  const int r16 = lane & 15;
  const int kg = lane >> 4;
  const int wr = w >> 1;
  const int wc = w & 1;

  const float* Afb = AFP32 ? Af + b * strideA : nullptr;
  const __hip_bfloat16* Abb = AFP32 ? nullptr : Ab + b * strideA;
  const __hip_bfloat16* Btb = Bt + b * strideB;
  float* Cb = C + (long)bz * strideC;

  const floatx4 vzero = {0.f, 0.f, 0.f, 0.f};
  floatx4 acc[4][4];
#pragma unroll
  for (int i = 0; i < 4; ++i)
#pragma unroll
    for (int j = 0; j < 4; ++j) acc[i][j] = vzero;

  const int arow = tid >> 1;
  const int ahalf = tid & 1;
  float f[16];
  if constexpr (AFP32) {
    const float* ar = Afb + (long)(m0 + arow) * lda + kb + ahalf * 16;
    *(float4*)(f + 0)  = *(const float4*)(ar + 0);
    *(float4*)(f + 4)  = *(const float4*)(ar + 4);
    *(float4*)(f + 8)  = *(const float4*)(ar + 8);
    *(float4*)(f + 12) = *(const float4*)(ar + 12);
  }

  for (int k0 = kb; k0 < kb + klen; k0 += BK) {
#pragma unroll
    for (int q = 0; q < 2; ++q) {
      const __hip_bfloat16* gb =
          Btb + (long)(n0 + w * 32 + q * 16 + (lane >> 2)) * ldb + k0 + (lane & 3) * 8;
      async_copy16(gb, &Bs[(w * 32 + q * 16) * BK]);
    }
    if constexpr (!AFP32) {
#pragma unroll
      for (int q = 0; q < 2; ++q) {
        const __hip_bfloat16* ga =
            Abb + (long)(m0 + w * 32 + q * 16 + (lane >> 2)) * lda + k0 + (lane & 3) * 8;
        async_copy16(ga, &As[(w * 32 + q * 16) * BK]);
      }
    } else {
      union { short8 v[2]; __hip_bfloat16 e[16]; } u;
#pragma unroll
      for (int t = 0; t < 16; ++t) u.e[t] = __float2bfloat16(f[t]);
      short8* dst = (short8*)&As[arow * BK + ahalf * 16];
      dst[0] = u.v[0];
      dst[1] = u.v[1];
    }
    __syncthreads();

    if constexpr (AFP32) {
      if (k0 + BK < kb + klen) {
        const float* ar = Afb + (long)(m0 + arow) * lda + (k0 + BK) + ahalf * 16;
        *(float4*)(f + 0)  = *(const float4*)(ar + 0);
        *(float4*)(f + 4)  = *(const float4*)(ar + 4);
        *(float4*)(f + 8)  = *(const float4*)(ar + 8);
        *(float4*)(f + 12) = *(const float4*)(ar + 12);
      }
    }

    short8 a[4], bfrag[4];
#pragma unroll
    for (int i = 0; i < 4; ++i)
      a[i] = *(const short8*)&As[(wr * 64 + i * 16 + r16) * BK + kg * 8];
#pragma unroll
    for (int j = 0; j < 4; ++j)
      bfrag[j] = *(const short8*)&Bs[(wc * 64 + j * 16 + r16) * BK + kg * 8];
#pragma unroll
    for (int i = 0; i < 4; ++i)
#pragma unroll
      for (int j = 0; j < 4; ++j)
        acc[i][j] = __builtin_amdgcn_mfma_f32_16x16x32_bf16(a[i], bfrag[j], acc[i][j], 0, 0, 0);
    __syncthreads();
  }

  // epilogue: row = kg*4 + r, col = r16 (m89-verified C/D map)
#pragma unroll
  for (int i = 0; i < 4; ++i) {
    const int row_base = m0 + wr * 64 + i * 16 + kg * 4;
#pragma unroll
    for (int j = 0; j < 4; ++j) {
      const int col = n0 + wc * 64 + j * 16 + r16;
#pragma unroll
      for (int r = 0; r < 4; ++r)
        Cb[(long)(row_base + r) * ldc + col] = acc[i][j][r];
    }
  }
}

// ---------------- kr: reduce NSPLIT fp32 partials -> bf16 gram --------------
template <int NSPLIT>
__global__ __launch_bounds__(256) void reduce_cast_kernel(
    const float* __restrict__ P, __hip_bfloat16* __restrict__ G) {
  const int DD4 = DIM * DIM / 4;
  const long idx = (long)blockIdx.x * 256 + threadIdx.x;
  const int b = (int)(idx / DD4);
  const int e = (int)(idx % DD4);
  const float4* base = (const float4*)P + (long)(b * NSPLIT) * DD4 + e;
  float4 s = base[0];
#pragma unroll
  for (int p = 1; p < NSPLIT; ++p) {
    float4 t = base[(long)p * DD4];
    s.x += t.x; s.y += t.y; s.z += t.z; s.w += t.w;
  }
  union { short s4[4]; uint2 v; } u;
  u.s4[0] = __bfloat16_as_short(__float2bfloat16(s.x));
  u.s4[1] = __bfloat16_as_short(__float2bfloat16(s.y));
  u.s4[2] = __bfloat16_as_short(__float2bfloat16(s.z));
  u.s4[3] = __bfloat16_as_short(__float2bfloat16(s.w));
  *(uint2*)&G[idx * 4] = u.v;
}

// ---------------- host launch ----------------------------------------------
extern "C" void kernel_launch(void* const* d_in, const int* in_sizes, int n_in,
                              void* d_out, int out_size, void* d_ws, size_t ws_size,
                              hipStream_t stream) {
  const float* X = (const float*)d_in[0];
  float* out = (float*)d_out;
  const long xtBytes = (long)BATCH * DIM * SEQ * 2;        // 33.5 MB
  const long gramBytes = (long)BATCH * DIM * DIM * 2;      // 4.2 MB
  const long part8Bytes = (long)BATCH * 8 * DIM * DIM * 4; // 67 MB
  __hip_bfloat16* Xt = (__hip_bfloat16*)d_out;
  __hip_bfloat16* gram = (__hip_bfloat16*)d_ws;

  const bool bigWs = ws_size >= (size_t)(gramBytes + xtBytes + part8Bytes);
  const bool midWs = ws_size >= (size_t)(gramBytes + xtBytes);
  __hip_bfloat16* Xb16 = midWs ? (__hip_bfloat16*)((char*)d_ws + gramBytes) : nullptr;

  // k1: Xt[b][d][s] (+ Xb16[b][s][d] if ws fits)
  transpose_cast_kernel<<<dim3(SEQ / 64, DIM / 64, BATCH), 256, 0, stream>>>(X, Xt, Xb16);

  if (bigWs) {
    // k2: split-8, XCD-swizzled, partials in ws
    float* partials = (float*)((char*)d_ws + gramBytes + xtBytes);
    gemm_bt_kernel<8, false, 2><<<dim3(BATCH * 8, 16, 1), 256, 0, stream>>>(
        nullptr, Xt, Xt, partials, SEQ, SEQ, SEQ, DIM,
        (long)DIM * SEQ, (long)DIM * SEQ, (long)DIM * DIM);
    reduce_cast_kernel<8><<<dim3(BATCH * DIM * DIM / 4 / 256), 256, 0, stream>>>(
        partials, gram);
  } else {
    // fallback: split-4, partials in d_out upper half
    float* partials = (float*)((char*)d_out + xtBytes);
    gemm_bt_kernel<4, false, 2><<<dim3(BATCH * 4, 16, 1), 256, 0, stream>>>(
        nullptr, Xt, Xt, partials, SEQ, SEQ, SEQ, DIM,
        (long)DIM * SEQ, (long)DIM * SEQ, (long)DIM * DIM);
    reduce_cast_kernel<4><<<dim3(BATCH * DIM * DIM / 4 / 256), 256, 0, stream>>>(
        partials, gram);
  }

  // k3: out = A . gram^T (M=4096, N=512, K=512), XCD-swizzled
  if (midWs) {
    gemm_bt_kernel<1, false, 1><<<dim3(128, 1, BATCH), 256, 0, stream>>>(
        nullptr, Xb16, gram, out, DIM, DIM, DIM, DIM,
        (long)SEQ * DIM, (long)DIM * DIM, (long)SEQ * DIM);
  } else {
    gemm_bt_kernel<1, true, 1><<<dim3(128, 1, BATCH), 256, 0, stream>>>(
        X, nullptr, gram, out, DIM, DIM, DIM, DIM,
        (long)SEQ * DIM, (long)DIM * DIM, (long)SEQ * DIM);
  }
}

// Round 5
// 172.003 us; speedup vs baseline: 1.1442x; 1.1442x over previous
//
#include <hip/hip_runtime.h>
#include <hip/hip_bf16.h>

// out[b] = X[b] @ (X[b]^T @ X[b]);  B=8, S=4096, D=512, fp32 in/out.
// Pipeline (bf16 MFMA, fp32 accumulate), ws = 268MB observed:
//   k1: Xt[d][s] bf16 -> d_out[0:33.5M) ; Xb16[s][d] bf16 -> ws+4.2M
//   k2: split-K=4 gram partials fp32 -> ws+37.7M (XCD-swizzled, LDS double-buffered)
//   kr: reduce 4 partials -> bf16 gram -> ws[0:4.2M)
//   k3: out = Xb16 . gram^T (both K-contig, async-LDS dbuf, XCD-swizzled) -> d_out

typedef __attribute__((ext_vector_type(8))) short short8;
typedef __attribute__((ext_vector_type(4))) float floatx4;

#define BM 128
#define BN 128
#define BK 32

#define BATCH 8
#define SEQ 4096
#define DIM 512

__device__ __forceinline__ void async_copy16(const __hip_bfloat16* g, __hip_bfloat16* l) {
  __builtin_amdgcn_global_load_lds((const __attribute__((address_space(1))) void*)g,
                                   (__attribute__((address_space(3))) void*)l, 16, 0, 0);
}

// ---------------- k1: transpose+cast (Xt) and optional straight cast (Xb16) --
__global__ __launch_bounds__(256) void transpose_cast_kernel(
    const float* __restrict__ X, __hip_bfloat16* __restrict__ Xt,
    __hip_bfloat16* __restrict__ Xb16) {
  __shared__ float tile[64][65];
  const int b = blockIdx.z;
  const int s0 = blockIdx.x * 64;
  const int d0 = blockIdx.y * 64;
  const int tid = threadIdx.x;
  const int tx = tid & 63;
  const int ty = tid >> 6;  // 0..3
  const float* Xb = X + (long)b * SEQ * DIM;
  __hip_bfloat16* Xtb = Xt + (long)b * DIM * SEQ;
#pragma unroll
  for (int r = 0; r < 64; r += 4)
    tile[r + ty][tx] = Xb[(long)(s0 + r + ty) * DIM + d0 + tx];
  __syncthreads();
  // Xt[d][s]: pack 8 consecutive s per 16B store.
#pragma unroll
  for (int it = 0; it < 2; ++it) {
    const int idx = it * 256 + tid;    // 0..511
    const int dl = idx >> 3;           // 0..63
    const int so = (idx & 7) * 8;      // 0,8,..,56
    union { short8 v; __hip_bfloat16 e[8]; } u;
#pragma unroll
    for (int j = 0; j < 8; ++j) u.e[j] = __float2bfloat16(tile[so + j][dl]);
    *(short8*)&Xtb[(long)(d0 + dl) * SEQ + s0 + so] = u.v;
  }
  // Xb16[s][d]: straight cast, pack 8 consecutive d per 16B store.
  if (Xb16 != nullptr) {
    __hip_bfloat16* Xcb = Xb16 + (long)b * SEQ * DIM;
#pragma unroll
    for (int it = 0; it < 2; ++it) {
      const int idx = it * 256 + tid;  // 0..511
      const int sl = idx >> 3;         // 0..63
      const int dc = idx & 7;          // 8-wide d chunk
      union { short8 v; __hip_bfloat16 e[8]; } u;
#pragma unroll
      for (int j = 0; j < 8; ++j) u.e[j] = __float2bfloat16(tile[sl][dc * 8 + j]);
      *(short8*)&Xcb[(long)(s0 + sl) * DIM + d0 + dc * 8] = u.v;
    }
  }
}

// ---------------- GEMM: C = A . Bt^T (Bt stored [N][K], K-contiguous) -------
// Double-buffered LDS: next tile's global_load_lds copies are issued right
// after the barrier that opens compute on the current buffer, so the
// vmcnt(0)-before-barrier drain waits on copies that already had one compute
// phase in flight.
// NSPLIT: split-K factor. AFP32: A fp32 cast-in-staging w/ register prefetch.
// SWZ=1: grid(128,1,B) k3-style: m-slab's 4 n-blocks share an XCD.
// SWZ=2: grid(B*NSPLIT,16,1) k2-style: one (b,split) chunk -> one XCD.
template <int NSPLIT, bool AFP32, int SWZ>
__global__ __launch_bounds__(256) void gemm_bt_kernel(
    const float* __restrict__ Af, const __hip_bfloat16* __restrict__ Ab,
    const __hip_bfloat16* __restrict__ Bt, float* __restrict__ C,
    int K, int lda, int ldb, int ldc, long strideA, long strideB, long strideC) {
  __shared__ __align__(16) __hip_bfloat16 As[2][BM * BK];  // [m][k]
  __shared__ __align__(16) __hip_bfloat16 Bs[2][BN * BK];  // [n][k]

  int bz, m0, n0;
  if constexpr (SWZ == 1) {
    const int lin = blockIdx.x;        // 0..127 per batch
    bz = blockIdx.z;
    const int xcd = lin & 7;
    const int t = lin >> 3;            // 0..15
    n0 = (t & 3) * BN;
    m0 = ((t >> 2) * 8 + xcd) * BM;
  } else if constexpr (SWZ == 2) {
    bz = blockIdx.x;                   // chunk id, fastest dim -> xcd = bz & 7
    const int t = blockIdx.y;          // 0..15 tile
    m0 = (t >> 2) * BM;
    n0 = (t & 3) * BN;
  } else {
    bz = blockIdx.z;
    m0 = blockIdx.y * BM;
    n0 = blockIdx.x * BN;
  }
  const int b = bz / NSPLIT;
  const int split = bz % NSPLIT;
  const int klen = K / NSPLIT;
  const int kb = split * klen;

  const int tid = threadIdx.x;
  const int w = tid >> 6;
  const int lane = tid & 63;
  const int r16 = lane & 15;
  const int kg = lane >> 4;
  const int wr = w >> 1;
  const int wc = w & 1;

  const float* Afb = AFP32 ? Af + b * strideA : nullptr;
  const __hip_bfloat16* Abb = AFP32 ? nullptr : Ab + b * strideA;
  const __hip_bfloat16* Btb = Bt + b * strideB;
  float* Cb = C + (long)bz * strideC;

  const floatx4 vzero = {0.f, 0.f, 0.f, 0.f};
  floatx4 acc[4][4];
#pragma unroll
  for (int i = 0; i < 4; ++i)
#pragma unroll
    for (int j = 0; j < 4; ++j) acc[i][j] = vzero;

  const int arow = tid >> 1;
  const int ahalf = tid & 1;
  float f[16];

  auto stageB = [&](int buf, int k0) {
#pragma unroll
    for (int q = 0; q < 2; ++q) {
      const __hip_bfloat16* gb =
          Btb + (long)(n0 + w * 32 + q * 16 + (lane >> 2)) * ldb + k0 + (lane & 3) * 8;
      async_copy16(gb, &Bs[buf][(w * 32 + q * 16) * BK]);
    }
  };
  auto stageA = [&](int buf, int k0) {
#pragma unroll
    for (int q = 0; q < 2; ++q) {
      const __hip_bfloat16* ga =
          Abb + (long)(m0 + w * 32 + q * 16 + (lane >> 2)) * lda + k0 + (lane & 3) * 8;
      async_copy16(ga, &As[buf][(w * 32 + q * 16) * BK]);
    }
  };
  auto loadF = [&](int k0) {
    const float* ar = Afb + (long)(m0 + arow) * lda + k0 + ahalf * 16;
    *(float4*)(f + 0)  = *(const float4*)(ar + 0);
    *(float4*)(f + 4)  = *(const float4*)(ar + 4);
    *(float4*)(f + 8)  = *(const float4*)(ar + 8);
    *(float4*)(f + 12) = *(const float4*)(ar + 12);
  };
  auto writeF = [&](int buf) {
    union { short8 v[2]; __hip_bfloat16 e[16]; } u;
#pragma unroll
    for (int t = 0; t < 16; ++t) u.e[t] = __float2bfloat16(f[t]);
    short8* dst = (short8*)&As[buf][arow * BK + ahalf * 16];
    dst[0] = u.v[0];
    dst[1] = u.v[1];
  };

  const int nIter = klen / BK;
  // prologue: fill buffer 0
  if constexpr (AFP32) {
    loadF(kb);
    writeF(0);
    loadF(kb + BK);  // prefetch tile 1 into registers
  } else {
    stageA(0, kb);
  }
  stageB(0, kb);

  for (int t = 0; t < nIter; ++t) {
    const int cur = t & 1;
    __syncthreads();  // drains vmcnt/lgkm: buffer `cur` is ready
    // issue next tile into the other buffer; it stays in flight during compute
    if (t + 1 < nIter) {
      if constexpr (AFP32) {
        writeF(cur ^ 1);                         // ds_write (lgkm), disjoint buffer
        if (t + 2 < nIter) loadF(kb + (t + 2) * BK);  // global prefetch for t+2
      } else {
        stageA(cur ^ 1, kb + (t + 1) * BK);
      }
      stageB(cur ^ 1, kb + (t + 1) * BK);
    }

    short8 a[4], bfrag[4];
#pragma unroll
    for (int i = 0; i < 4; ++i)
      a[i] = *(const short8*)&As[cur][(wr * 64 + i * 16 + r16) * BK + kg * 8];
#pragma unroll
    for (int j = 0; j < 4; ++j)
      bfrag[j] = *(const short8*)&Bs[cur][(wc * 64 + j * 16 + r16) * BK + kg * 8];
#pragma unroll
    for (int i = 0; i < 4; ++i)
#pragma unroll
      for (int j = 0; j < 4; ++j)
        acc[i][j] = __builtin_amdgcn_mfma_f32_16x16x32_bf16(a[i], bfrag[j], acc[i][j], 0, 0, 0);
  }

  // epilogue: row = kg*4 + r, col = r16 (m89-verified C/D map)
#pragma unroll
  for (int i = 0; i < 4; ++i) {
    const int row_base = m0 + wr * 64 + i * 16 + kg * 4;
#pragma unroll
    for (int j = 0; j < 4; ++j) {
      const int col = n0 + wc * 64 + j * 16 + r16;
#pragma unroll
      for (int r = 0; r < 4; ++r)
        Cb[(long)(row_base + r) * ldc + col] = acc[i][j][r];
    }
  }
}

// ---------------- kr: reduce NSPLIT fp32 partials -> bf16 gram --------------
template <int NSPLIT>
__global__ __launch_bounds__(256) void reduce_cast_kernel(
    const float* __restrict__ P, __hip_bfloat16* __restrict__ G) {
  const int DD4 = DIM * DIM / 4;
  const long idx = (long)blockIdx.x * 256 + threadIdx.x;
  const int b = (int)(idx / DD4);
  const int e = (int)(idx % DD4);
  const float4* base = (const float4*)P + (long)(b * NSPLIT) * DD4 + e;
  float4 s = base[0];
#pragma unroll
  for (int p = 1; p < NSPLIT; ++p) {
    float4 t = base[(long)p * DD4];
    s.x += t.x; s.y += t.y; s.z += t.z; s.w += t.w;
  }
  union { short s4[4]; uint2 v; } u;
  u.s4[0] = __bfloat16_as_short(__float2bfloat16(s.x));
  u.s4[1] = __bfloat16_as_short(__float2bfloat16(s.y));
  u.s4[2] = __bfloat16_as_short(__float2bfloat16(s.z));
  u.s4[3] = __bfloat16_as_short(__float2bfloat16(s.w));
  *(uint2*)&G[idx * 4] = u.v;
}

// ---------------- host launch ----------------------------------------------
extern "C" void kernel_launch(void* const* d_in, const int* in_sizes, int n_in,
                              void* d_out, int out_size, void* d_ws, size_t ws_size,
                              hipStream_t stream) {
  const float* X = (const float*)d_in[0];
  float* out = (float*)d_out;
  const long xtBytes = (long)BATCH * DIM * SEQ * 2;        // 33.5 MB
  const long gramBytes = (long)BATCH * DIM * DIM * 2;      // 4.2 MB
  const long part4Bytes = (long)BATCH * 4 * DIM * DIM * 4; // 33.5 MB
  __hip_bfloat16* Xt = (__hip_bfloat16*)d_out;
  __hip_bfloat16* gram = (__hip_bfloat16*)d_ws;

  const bool bigWs = ws_size >= (size_t)(gramBytes + xtBytes + part4Bytes);
  const bool midWs = ws_size >= (size_t)(gramBytes + xtBytes);
  __hip_bfloat16* Xb16 = midWs ? (__hip_bfloat16*)((char*)d_ws + gramBytes) : nullptr;

  // k1: Xt[b][d][s] (+ Xb16[b][s][d] if ws fits)
  transpose_cast_kernel<<<dim3(SEQ / 64, DIM / 64, BATCH), 256, 0, stream>>>(X, Xt, Xb16);

  // k2: split-4 gram partials, XCD-swizzled, double-buffered
  float* partials = bigWs ? (float*)((char*)d_ws + gramBytes + xtBytes)
                          : (float*)((char*)d_out + xtBytes);
  gemm_bt_kernel<4, false, 2><<<dim3(BATCH * 4, 16, 1), 256, 0, stream>>>(
      nullptr, Xt, Xt, partials, SEQ, SEQ, SEQ, DIM,
      (long)DIM * SEQ, (long)DIM * SEQ, (long)DIM * DIM);
  reduce_cast_kernel<4><<<dim3(BATCH * DIM * DIM / 4 / 256), 256, 0, stream>>>(
      partials, gram);

  // k3: out = A . gram^T (M=4096, N=512, K=512), XCD-swizzled, double-buffered
  if (midWs) {
    gemm_bt_kernel<1, false, 1><<<dim3(128, 1, BATCH), 256, 0, stream>>>(
        nullptr, Xb16, gram, out, DIM, DIM, DIM, DIM,
        (long)SEQ * DIM, (long)DIM * DIM, (long)SEQ * DIM);
  } else {
    gemm_bt_kernel<1, true, 1><<<dim3(128, 1, BATCH), 256, 0, stream>>>(
        X, nullptr, gram, out, DIM, DIM, DIM, DIM,
        (long)SEQ * DIM, (long)DIM * DIM, (long)SEQ * DIM);
  }
}

// Round 6
// 169.473 us; speedup vs baseline: 1.1613x; 1.0149x over previous
//
#include <hip/hip_runtime.h>
#include <hip/hip_bf16.h>
#include <type_traits>

// out[b] = X[b] @ (X[b]^T @ X[b]);  B=8, S=4096, D=512, fp32 in/out.
// Pipeline (bf16 MFMA, fp32 accumulate), ws = 268MB observed:
//   k1: Xt[d][s] bf16 -> d_out[0:33.5M) ; Xb16[s][d] bf16 -> ws+4.2M
//   k2: split-K=4 gram partials bf16 -> ws+37.7M (XCD-swizzled, LDS dbuf)
//   kr: reduce 4 bf16 partials -> bf16 gram -> ws[0:4.2M)
//   k3: out = Xb16 . gram^T (both K-contig, async-LDS dbuf, XCD-swizzled) -> d_out

typedef __attribute__((ext_vector_type(8))) short short8;
typedef __attribute__((ext_vector_type(4))) float floatx4;

#define BM 128
#define BN 128
#define BK 32

#define BATCH 8
#define SEQ 4096
#define DIM 512

__device__ __forceinline__ void async_copy16(const __hip_bfloat16* g, __hip_bfloat16* l) {
  __builtin_amdgcn_global_load_lds((const __attribute__((address_space(1))) void*)g,
                                   (__attribute__((address_space(3))) void*)l, 16, 0, 0);
}

// ---------------- k1: transpose+cast (Xt) and optional straight cast (Xb16) --
__global__ __launch_bounds__(256) void transpose_cast_kernel(
    const float* __restrict__ X, __hip_bfloat16* __restrict__ Xt,
    __hip_bfloat16* __restrict__ Xb16) {
  __shared__ float tile[64][65];
  const int b = blockIdx.z;
  const int s0 = blockIdx.x * 64;
  const int d0 = blockIdx.y * 64;
  const int tid = threadIdx.x;
  const int tx = tid & 63;
  const int ty = tid >> 6;  // 0..3
  const float* Xb = X + (long)b * SEQ * DIM;
  __hip_bfloat16* Xtb = Xt + (long)b * DIM * SEQ;
#pragma unroll
  for (int r = 0; r < 64; r += 4)
    tile[r + ty][tx] = Xb[(long)(s0 + r + ty) * DIM + d0 + tx];
  __syncthreads();
  // Xt[d][s]: pack 8 consecutive s per 16B store.
#pragma unroll
  for (int it = 0; it < 2; ++it) {
    const int idx = it * 256 + tid;    // 0..511
    const int dl = idx >> 3;           // 0..63
    const int so = (idx & 7) * 8;      // 0,8,..,56
    union { short8 v; __hip_bfloat16 e[8]; } u;
#pragma unroll
    for (int j = 0; j < 8; ++j) u.e[j] = __float2bfloat16(tile[so + j][dl]);
    *(short8*)&Xtb[(long)(d0 + dl) * SEQ + s0 + so] = u.v;
  }
  // Xb16[s][d]: straight cast, pack 8 consecutive d per 16B store.
  if (Xb16 != nullptr) {
    __hip_bfloat16* Xcb = Xb16 + (long)b * SEQ * DIM;
#pragma unroll
    for (int it = 0; it < 2; ++it) {
      const int idx = it * 256 + tid;  // 0..511
      const int sl = idx >> 3;         // 0..63
      const int dc = idx & 7;          // 8-wide d chunk
      union { short8 v; __hip_bfloat16 e[8]; } u;
#pragma unroll
      for (int j = 0; j < 8; ++j) u.e[j] = __float2bfloat16(tile[sl][dc * 8 + j]);
      *(short8*)&Xcb[(long)(s0 + sl) * DIM + d0 + dc * 8] = u.v;
    }
  }
}

// ---------------- GEMM: C = A . Bt^T (Bt stored [N][K], K-contiguous) -------
// Double-buffered LDS: next tile's global_load_lds copies are issued right
// after the barrier that opens compute on the current buffer.
// __launch_bounds__(256,4): force <=128 unified regs/wave -> 4 blocks/CU.
// NSPLIT: split-K factor. AFP32: A fp32 cast-in-staging w/ register prefetch.
// CT: C element type (float or bf16).
// SWZ=1: grid(128,1,B) k3-style: m-slab's 4 n-blocks share an XCD.
// SWZ=2: grid(B*NSPLIT,16,1) k2-style: one (b,split) chunk -> one XCD.
template <int NSPLIT, bool AFP32, int SWZ, typename CT>
__global__ __launch_bounds__(256, 4) void gemm_bt_kernel(
    const float* __restrict__ Af, const __hip_bfloat16* __restrict__ Ab,
    const __hip_bfloat16* __restrict__ Bt, CT* __restrict__ C,
    int K, int lda, int ldb, int ldc, long strideA, long strideB, long strideC) {
  __shared__ __align__(16) __hip_bfloat16 As[2][BM * BK];  // [m][k]
  __shared__ __align__(16) __hip_bfloat16 Bs[2][BN * BK];  // [n][k]

  int bz, m0, n0;
  if constexpr (SWZ == 1) {
    const int lin = blockIdx.x;        // 0..127 per batch
    bz = blockIdx.z;
    const int xcd = lin & 7;
    const int t = lin >> 3;            // 0..15
    n0 = (t & 3) * BN;
    m0 = ((t >> 2) * 8 + xcd) * BM;
  } else if constexpr (SWZ == 2) {
    bz = blockIdx.x;                   // chunk id, fastest dim -> xcd = bz & 7
    const int t = blockIdx.y;          // 0..15 tile
    m0 = (t >> 2) * BM;
    n0 = (t & 3) * BN;
  } else {
    bz = blockIdx.z;
    m0 = blockIdx.y * BM;
    n0 = blockIdx.x * BN;
  }
  const int b = bz / NSPLIT;
  const int split = bz % NSPLIT;
  const int klen = K / NSPLIT;
  const int kb = split * klen;

  const int tid = threadIdx.x;
  const int w = tid >> 6;
  const int lane = tid & 63;
  const int r16 = lane & 15;
  const int kg = lane >> 4;
  const int wr = w >> 1;
  const int wc = w & 1;

  const float* Afb = AFP32 ? Af + b * strideA : nullptr;
  const __hip_bfloat16* Abb = AFP32 ? nullptr : Ab + b * strideA;
  const __hip_bfloat16* Btb = Bt + b * strideB;
  CT* Cb = C + (long)bz * strideC;

  const floatx4 vzero = {0.f, 0.f, 0.f, 0.f};
  floatx4 acc[4][4];
#pragma unroll
  for (int i = 0; i < 4; ++i)
#pragma unroll
    for (int j = 0; j < 4; ++j) acc[i][j] = vzero;

  const int arow = tid >> 1;
  const int ahalf = tid & 1;
  float f[16];

  auto stageB = [&](int buf, int k0) {
#pragma unroll
    for (int q = 0; q < 2; ++q) {
      const __hip_bfloat16* gb =
          Btb + (long)(n0 + w * 32 + q * 16 + (lane >> 2)) * ldb + k0 + (lane & 3) * 8;
      async_copy16(gb, &Bs[buf][(w * 32 + q * 16) * BK]);
    }
  };
  auto stageA = [&](int buf, int k0) {
#pragma unroll
    for (int q = 0; q < 2; ++q) {
      const __hip_bfloat16* ga =
          Abb + (long)(m0 + w * 32 + q * 16 + (lane >> 2)) * lda + k0 + (lane & 3) * 8;
      async_copy16(ga, &As[buf][(w * 32 + q * 16) * BK]);
    }
  };
  auto loadF = [&](int k0) {
    const float* ar = Afb + (long)(m0 + arow) * lda + k0 + ahalf * 16;
    *(float4*)(f + 0)  = *(const float4*)(ar + 0);
    *(float4*)(f + 4)  = *(const float4*)(ar + 4);
    *(float4*)(f + 8)  = *(const float4*)(ar + 8);
    *(float4*)(f + 12) = *(const float4*)(ar + 12);
  };
  auto writeF = [&](int buf) {
    union { short8 v[2]; __hip_bfloat16 e[16]; } u;
#pragma unroll
    for (int t = 0; t < 16; ++t) u.e[t] = __float2bfloat16(f[t]);
    short8* dst = (short8*)&As[buf][arow * BK + ahalf * 16];
    dst[0] = u.v[0];
    dst[1] = u.v[1];
  };

  const int nIter = klen / BK;
  // prologue: fill buffer 0
  if constexpr (AFP32) {
    loadF(kb);
    writeF(0);
    loadF(kb + BK);  // prefetch tile 1 into registers
  } else {
    stageA(0, kb);
  }
  stageB(0, kb);

  for (int t = 0; t < nIter; ++t) {
    const int cur = t & 1;
    __syncthreads();  // drains vmcnt/lgkm: buffer `cur` is ready
    // issue next tile into the other buffer; it stays in flight during compute
    if (t + 1 < nIter) {
      if constexpr (AFP32) {
        writeF(cur ^ 1);
        if (t + 2 < nIter) loadF(kb + (t + 2) * BK);
      } else {
        stageA(cur ^ 1, kb + (t + 1) * BK);
      }
      stageB(cur ^ 1, kb + (t + 1) * BK);
    }

    short8 a[4], bfrag[4];
#pragma unroll
    for (int i = 0; i < 4; ++i)
      a[i] = *(const short8*)&As[cur][(wr * 64 + i * 16 + r16) * BK + kg * 8];
#pragma unroll
    for (int j = 0; j < 4; ++j)
      bfrag[j] = *(const short8*)&Bs[cur][(wc * 64 + j * 16 + r16) * BK + kg * 8];
#pragma unroll
    for (int i = 0; i < 4; ++i)
#pragma unroll
      for (int j = 0; j < 4; ++j)
        acc[i][j] = __builtin_amdgcn_mfma_f32_16x16x32_bf16(a[i], bfrag[j], acc[i][j], 0, 0, 0);
  }

  // epilogue: row = kg*4 + r, col = r16 (m89-verified C/D map)
#pragma unroll
  for (int i = 0; i < 4; ++i) {
    const int row_base = m0 + wr * 64 + i * 16 + kg * 4;
#pragma unroll
    for (int j = 0; j < 4; ++j) {
      const int col = n0 + wc * 64 + j * 16 + r16;
#pragma unroll
      for (int r = 0; r < 4; ++r) {
        const float v = acc[i][j][r];
        if constexpr (std::is_same<CT, float>::value)
          Cb[(long)(row_base + r) * ldc + col] = v;
        else
          Cb[(long)(row_base + r) * ldc + col] = __float2bfloat16(v);
      }
    }
  }
}

// ---------------- kr: reduce NSPLIT bf16 partials -> bf16 gram --------------
template <int NSPLIT>
__global__ __launch_bounds__(256) void reduce_cast_kernel(
    const __hip_bfloat16* __restrict__ P, __hip_bfloat16* __restrict__ G) {
  const int DD8 = DIM * DIM / 8;  // 16B-vector count per [b][split]
  const long idx = (long)blockIdx.x * 256 + threadIdx.x;  // 0 .. B*DD8
  const int b = (int)(idx / DD8);
  const int e = (int)(idx % DD8);
  const __hip_bfloat16* base = P + (long)(b * NSPLIT) * DIM * DIM + (long)e * 8;
  float s[8] = {0.f, 0.f, 0.f, 0.f, 0.f, 0.f, 0.f, 0.f};
#pragma unroll
  for (int p = 0; p < NSPLIT; ++p) {
    union { short8 v; __hip_bfloat16 e8[8]; } u;
    u.v = *(const short8*)(base + (long)p * DIM * DIM);
#pragma unroll
    for (int j = 0; j < 8; ++j) s[j] += __bfloat162float(u.e8[j]);
  }
  union { short8 v; __hip_bfloat16 e8[8]; } o;
#pragma unroll
  for (int j = 0; j < 8; ++j) o.e8[j] = __float2bfloat16(s[j]);
  *(short8*)&G[(long)idx * 8] = o.v;
}

// ---------------- host launch ----------------------------------------------
extern "C" void kernel_launch(void* const* d_in, const int* in_sizes, int n_in,
                              void* d_out, int out_size, void* d_ws, size_t ws_size,
                              hipStream_t stream) {
  const float* X = (const float*)d_in[0];
  float* out = (float*)d_out;
  const long xtBytes = (long)BATCH * DIM * SEQ * 2;          // 33.5 MB
  const long gramBytes = (long)BATCH * DIM * DIM * 2;        // 4.2 MB
  const long partBytes = (long)BATCH * 4 * DIM * DIM * 2;    // 16.8 MB (bf16)
  __hip_bfloat16* Xt = (__hip_bfloat16*)d_out;
  __hip_bfloat16* gram = (__hip_bfloat16*)d_ws;

  const bool bigWs = ws_size >= (size_t)(gramBytes + xtBytes + partBytes);
  const bool midWs = ws_size >= (size_t)(gramBytes + xtBytes);
  __hip_bfloat16* Xb16 = midWs ? (__hip_bfloat16*)((char*)d_ws + gramBytes) : nullptr;

  // k1: Xt[b][d][s] (+ Xb16[b][s][d] if ws fits)
  transpose_cast_kernel<<<dim3(SEQ / 64, DIM / 64, BATCH), 256, 0, stream>>>(X, Xt, Xb16);

  // k2: split-4 gram partials (bf16), XCD-swizzled, double-buffered
  __hip_bfloat16* partials = bigWs
      ? (__hip_bfloat16*)((char*)d_ws + gramBytes + xtBytes)
      : (__hip_bfloat16*)((char*)d_out + xtBytes);
  gemm_bt_kernel<4, false, 2, __hip_bfloat16>
      <<<dim3(BATCH * 4, 16, 1), 256, 0, stream>>>(
          nullptr, Xt, Xt, partials, SEQ, SEQ, SEQ, DIM,
          (long)DIM * SEQ, (long)DIM * SEQ, (long)DIM * DIM);
  reduce_cast_kernel<4><<<dim3(BATCH * DIM * DIM / 8 / 256), 256, 0, stream>>>(
      partials, gram);

  // k3: out = A . gram^T (M=4096, N=512, K=512), XCD-swizzled, double-buffered
  if (midWs) {
    gemm_bt_kernel<1, false, 1, float><<<dim3(128, 1, BATCH), 256, 0, stream>>>(
        nullptr, Xb16, gram, out, DIM, DIM, DIM, DIM,
        (long)SEQ * DIM, (long)DIM * DIM, (long)SEQ * DIM);
  } else {
    gemm_bt_kernel<1, true, 1, float><<<dim3(128, 1, BATCH), 256, 0, stream>>>(
        X, nullptr, gram, out, DIM, DIM, DIM, DIM,
        (long)SEQ * DIM, (long)DIM * DIM, (long)SEQ * DIM);
  }
}